// Round 4
// baseline (121.801 us; speedup 1.0000x reference)
//
#include <hip/hip_runtime.h>
#include <hip/hip_bf16.h>
#include <math.h>

// Problem constants (from reference): B=4, S=2048, E=512, H=8, DK=64
#define B_ 4
#define S_ 2048
#define E_ 512
#define H_ 8
#define DK_ 64

typedef __attribute__((ext_vector_type(8))) short short8;    // 8x16b (4 VGPRs)
typedef __attribute__((ext_vector_type(4))) float f32x4;     // MFMA C/D frag
typedef _Float16 half8 __attribute__((ext_vector_type(8)));  // 8 f16
typedef _Float16 half4 __attribute__((ext_vector_type(4)));  // 4 f16
typedef __fp16 fp16x2 __attribute__((ext_vector_type(2)));   // cvt_pkrtz result
typedef unsigned uint4v __attribute__((ext_vector_type(4)));

__device__ inline short8 ld8(const void* p) {
  return *reinterpret_cast<const short8*>(p);
}
__device__ inline half8 ld8h(const void* p) {
  return *reinterpret_cast<const half8*>(p);
}

static __device__ inline unsigned pk2(float a, float b) {
  fp16x2 h = __builtin_amdgcn_cvt_pkrtz(a, b);  // v_cvt_pkrtz_f16_f32
  return __builtin_bit_cast(unsigned, h);
}
static __device__ inline half8 pack8(float p0, float p1, float p2, float p3,
                                     float p4, float p5, float p6, float p7) {
  uint4v u;
  u[0] = pk2(p0, p1); u[1] = pk2(p2, p3);
  u[2] = pk2(p4, p5); u[3] = pk2(p6, p7);
  return __builtin_bit_cast(half8, u);
}

// ---------------------------------------------------------------------------
// Fragment-order layouts (R8/R9): kA = QK A/B-operand order with the key
// permutation that makes QK C-tiles concatenate into the PV K=32 B-operand;
// vA = V^T A-operand order. Waves load frags as coalesced 1KB dwordx4. No
// LDS, no barriers (except drift-control s_barrier) in the attention K-loop.
// R13 LESSON: 32-row q-blocks double per-MFMA load overhead; q-tile stays 64.
// R16: tail fix (all attn blocks co-resident) measured -3.1 us -> attn now at
// its L2-BW floor (512 MB / ~35 TB/s ~= 14 us).
// R17 (this round): L1 PAIRING — 4 waves/block over 128 q-rows (2 tiles);
// wave w: tile w>>1, key-half w&1. Waves (0,2) and (1,3) read IDENTICAL K/V
// addresses -> per-CU L1 serves the second wave -> block pulls K+V from L2
// once (512 KB) not twice. Total L2 reads 512 -> 256 MB. Raw s_barrier per
// K-iter bounds pair drift. Per-wave math identical to R16.
// ---------------------------------------------------------------------------

// ---------------------------------------------------------------------------
// Kernel 1: cos(x+theta) -> kA (frag order, serves Q and K) + vA (frag order).
// Band blockIdx.y == B*H additionally converts W (fp32) -> wb (f16).
// ---------------------------------------------------------------------------
__global__ __launch_bounds__(256) void prep_g_kernel(
    const float* __restrict__ x, const float* __restrict__ theta,
    const float* __restrict__ W, _Float16* __restrict__ kA,
    _Float16* __restrict__ vA, _Float16* __restrict__ wb) {
  const int tid = threadIdx.x;

  // ---- fused prep_w band: 32 blocks convert E*E = 262144 floats -> f16 ----
  if (blockIdx.y == B_ * H_) {
    const int base = (blockIdx.x * 256 + tid) * 8;
#pragma unroll
    for (int it = 0; it < 4; ++it) {
      const int i = base + it * 65536;
      float4 a = *reinterpret_cast<const float4*>(W + i);
      float4 c = *reinterpret_cast<const float4*>(W + i + 4);
      half8 v;
      v[0]=(_Float16)a.x; v[1]=(_Float16)a.y; v[2]=(_Float16)a.z; v[3]=(_Float16)a.w;
      v[4]=(_Float16)c.x; v[5]=(_Float16)c.y; v[6]=(_Float16)c.z; v[7]=(_Float16)c.w;
      *reinterpret_cast<half8*>(wb + i) = v;
    }
    return;
  }

  const int bh = blockIdx.y;
  const int b = bh >> 3, h = bh & 7;
  const int s0 = blockIdx.x * 64;
  const int wave = tid >> 6, lane = tid & 63;
  const int col = lane & 15, quad = lane >> 4;
  __shared__ _Float16 tile[64 * 72];

  // float4 x-loads (16B/lane, G13): thread's dc4 is iteration-invariant, so
  // theta loads hoist to 4 registers.
  const float* xp = x + ((size_t)(b * S_ + s0)) * E_ + h * DK_;
  const int dc4 = (tid & 15) * 4;
  const float4 th = *reinterpret_cast<const float4*>(theta + dc4);
#pragma unroll
  for (int it = 0; it < 4; ++it) {
    const int sr = it * 16 + (tid >> 4);
    float4 xv = *reinterpret_cast<const float4*>(xp + (size_t)sr * E_ + dc4);
    half4 hv;
    hv[0] = (_Float16)__cosf(xv.x + th.x);
    hv[1] = (_Float16)__cosf(xv.y + th.y);
    hv[2] = (_Float16)__cosf(xv.z + th.z);
    hv[3] = (_Float16)__cosf(xv.w + th.w);
    *reinterpret_cast<half4*>(tile + sr * 72 + dc4) = hv;
  }
  __syncthreads();

  _Float16* kb = kA + (size_t)bh * (S_ * DK_);
  _Float16* vb = vA + (size_t)bh * (S_ * DK_);
  const int Gbase = s0 >> 5;
  // kA: 8 chunks (2 Gl x 2 g x 2 hh); wave handles chunk wave + it2*4
#pragma unroll
  for (int it2 = 0; it2 < 2; ++it2) {
    int c = wave + it2 * 4;
    int Gl = c >> 2, g = (c >> 1) & 1, hh = c & 1;
    int ploc = Gl * 32 + ((col >> 2) << 3) + g * 4 + (col & 3);
    half8 v = ld8h(tile + ploc * 72 + hh * 32 + quad * 8);
    *reinterpret_cast<half8*>(
        kb + ((size_t)(Gbase + Gl) * 2048 + (g * 2 + hh) * 512 + lane * 8)) = v;
  }
  // vA: 8 chunks (2 Gl x 4 dcc); transposed gather from tile
#pragma unroll
  for (int it2 = 0; it2 < 2; ++it2) {
    int c = wave + it2 * 4;
    int Gl = c >> 2, dcc = c & 3;
    half8 v;
#pragma unroll
    for (int j = 0; j < 8; ++j)
      v[j] = tile[(Gl * 32 + quad * 8 + j) * 72 + dcc * 16 + col];
    *reinterpret_cast<half8*>(
        vb + ((size_t)(Gbase + Gl) * 2048 + dcc * 512 + lane * 8)) = v;
  }
}

// ---------------------------------------------------------------------------
// Kernel 2: attention — R17: 512 blocks x 256 threads (4 waves = 2 q-tiles x
// 2 key-halves). Waves sharing a key-half read identical K/V -> L1 dedup.
// XCD swizzle: XCD x owns bh [4x,4x+4) (2 MB/XCD, L2-resident).
// ---------------------------------------------------------------------------
__global__ __launch_bounds__(256, 3) void attn_kernel(
    const _Float16* __restrict__ kA, const _Float16* __restrict__ vA,
    _Float16* __restrict__ ao) {
  const int tid = threadIdx.x;
  const int wave = tid >> 6, lane = tid & 63;
  const int col = lane & 15, quad = lane >> 4;
  const int wg = blockIdx.x + 32 * blockIdx.y;          // [0,512)
  const int xcd = wg & 7, slot = wg >> 3;               // slot in [0,64)
  const int bh = xcd * 4 + (slot >> 4);
  const int q0 = (slot & 15) * 128;                     // block's 128-row base
  const int t = wave >> 1;                              // q-tile within block
  const int kh = wave & 1;                              // key-half
  const int qt0 = q0 + t * 64;                          // wave's 64-row q-tile
  const _Float16* kb = kA + (size_t)bh * (S_ * DK_);
  const _Float16* vb = vA + (size_t)bh * (S_ * DK_);

  // Q frags: qc=(Gq,g): chunk ((qt0>>5)+Gq, g, h), scaled by C1
  const _Float16 hC1 = (_Float16)0.18033688011112042f;  // 0.125*log2(e)
  half8 qa[4][2];
#pragma unroll
  for (int qc = 0; qc < 4; ++qc)
#pragma unroll
    for (int hh = 0; hh < 2; ++hh)
      qa[qc][hh] = ld8h(kb + (size_t)((qt0 >> 5) + (qc >> 1)) * 2048 +
                        ((qc & 1) * 2 + hh) * 512 + lane * 8) * hC1;

  const half8 kOnes = {(_Float16)1, (_Float16)1, (_Float16)1, (_Float16)1,
                       (_Float16)1, (_Float16)1, (_Float16)1, (_Float16)1};

  f32x4 o[4][4];
  f32x4 ol[4];  // softmax denominators via ones-MFMA (rows redundant)
#pragma unroll
  for (int qc = 0; qc < 4; ++qc) {
#pragma unroll
    for (int dc = 0; dc < 4; ++dc) o[qc][dc] = f32x4{0.f, 0.f, 0.f, 0.f};
    ol[qc] = f32x4{0.f, 0.f, 0.f, 0.f};
  }

  // wave's key stripe: 1024 keys = 32 G-chunks (keys [kh*1024, kh*1024+1024))
  const _Float16* kw = kb + (size_t)kh * 32 * 2048 + lane * 8;
  const _Float16* vw = vb + (size_t)kh * 32 * 2048 + lane * 8;

  for (int it = 0; it < 32; ++it) {
    // drift control: waves (0,2) / (1,3) stream identical K/V addresses; the
    // barrier keeps them within L1 residency of each other. No LDS deps in
    // the loop, so this is a pure rendezvous (no waitcnt drain).
    __builtin_amdgcn_s_barrier();
    const _Float16* kit = kw + it * 2048;
    const _Float16* vit = vw + it * 2048;
    half8 kf00 = ld8h(kit);
    half8 kf01 = ld8h(kit + 512);
    half8 kf10 = ld8h(kit + 1024);
    half8 kf11 = ld8h(kit + 1536);
    half8 vf0 = ld8h(vit);
    half8 vf1 = ld8h(vit + 512);
    half8 vf2 = ld8h(vit + 1024);
    half8 vf3 = ld8h(vit + 1536);

#pragma unroll
    for (int qc = 0; qc < 4; ++qc) {
      f32x4 z0{0.f, 0.f, 0.f, 0.f}, z1{0.f, 0.f, 0.f, 0.f};
      __builtin_amdgcn_s_setprio(1);
      z0 = __builtin_amdgcn_mfma_f32_16x16x32_f16(kf00, qa[qc][0], z0, 0, 0, 0);
      z0 = __builtin_amdgcn_mfma_f32_16x16x32_f16(kf01, qa[qc][1], z0, 0, 0, 0);
      z1 = __builtin_amdgcn_mfma_f32_16x16x32_f16(kf10, qa[qc][0], z1, 0, 0, 0);
      z1 = __builtin_amdgcn_mfma_f32_16x16x32_f16(kf11, qa[qc][1], z1, 0, 0, 0);
      __builtin_amdgcn_s_setprio(0);
      float p0 = __builtin_amdgcn_exp2f(z0[0]);
      float p1 = __builtin_amdgcn_exp2f(z0[1]);
      float p2 = __builtin_amdgcn_exp2f(z0[2]);
      float p3 = __builtin_amdgcn_exp2f(z0[3]);
      float p4 = __builtin_amdgcn_exp2f(z1[0]);
      float p5 = __builtin_amdgcn_exp2f(z1[1]);
      float p6 = __builtin_amdgcn_exp2f(z1[2]);
      float p7 = __builtin_amdgcn_exp2f(z1[3]);
      half8 pf = pack8(p0, p1, p2, p3, p4, p5, p6, p7);
      __builtin_amdgcn_s_setprio(1);
      o[qc][0] = __builtin_amdgcn_mfma_f32_16x16x32_f16(vf0, pf, o[qc][0], 0, 0, 0);
      o[qc][1] = __builtin_amdgcn_mfma_f32_16x16x32_f16(vf1, pf, o[qc][1], 0, 0, 0);
      o[qc][2] = __builtin_amdgcn_mfma_f32_16x16x32_f16(vf2, pf, o[qc][2], 0, 0, 0);
      o[qc][3] = __builtin_amdgcn_mfma_f32_16x16x32_f16(vf3, pf, o[qc][3], 0, 0, 0);
      ol[qc] = __builtin_amdgcn_mfma_f32_16x16x32_f16(kOnes, pf, ol[qc], 0, 0, 0);
      __builtin_amdgcn_s_setprio(0);
    }
  }

  // ---- cross-wave reduction: within each pair (tile t: waves 2t, 2t+1) ----
  // ol[qc][0] holds this wave's 1024-key partial denominator for q=col
  // (quad-redundant). Pair regions are disjoint; barriers are block-wide.
  __shared__ float reds[4096];  // 16 KB (2 pair-regions x 2048 floats)
  float* pr = reds + t * 2048;
  const int pw = kh;  // wave index within pair
  if (quad == 0) {
#pragma unroll
    for (int qc = 0; qc < 4; ++qc) pr[(pw * 4 + qc) * 16 + col] = ol[qc][0];
  }
  __syncthreads();
  // wave pw reduces/stores qc = pw (passes 0,1) and qc = pw+2 (passes 2,3)
  float ltotA = pr[(0 * 4 + pw) * 16 + col] + pr[(1 * 4 + pw) * 16 + col];
  float ltotB = pr[(0 * 4 + pw + 2) * 16 + col] + pr[(1 * 4 + pw + 2) * 16 + col];
  float invA = __builtin_amdgcn_rcpf(ltotA);
  float invB = __builtin_amdgcn_rcpf(ltotB);

  const int b = bh >> 3, h = bh & 7;
  // store row carries the kA q-permutation: qc=(Gq,g), col -> q
  // qrow(qc) = qt0 + ((qc>>1)<<5) + ((col>>2)<<3) + (qc&1)*4 + (col&3)
  const int qrowA = qt0 + ((col >> 2) << 3) + pw * 4 + (col & 3);  // qc = pw
  const int qrowB = qrowA + 32;                                    // qc = pw+2
  _Float16* opA = ao + ((size_t)b * S_ + qrowA) * E_ + h * DK_;
  _Float16* opB = ao + ((size_t)b * S_ + qrowB) * E_ + h * DK_;
  __syncthreads();  // ltot reads done before reds is overwritten
#pragma unroll
  for (int p = 0; p < 4; ++p) {
    if (p) __syncthreads();  // previous pass's readers done
#pragma unroll
    for (int dc = 0; dc < 4; ++dc)
      *reinterpret_cast<f32x4*>(pr + pw * 1024 + lane * 16 + dc * 4) = o[p][dc];
    __syncthreads();
    if (pw == (p & 1)) {  // wave reduces its own qc (p<2: qc=pw; else pw+2)
      float invv = (p < 2) ? invA : invB;
      _Float16* op = (p < 2) ? opA : opB;
#pragma unroll
      for (int dc = 0; dc < 4; ++dc) {
        f32x4 acc = *reinterpret_cast<const f32x4*>(pr + lane * 16 + dc * 4);
        acc = acc + *reinterpret_cast<const f32x4*>(pr + 1024 + lane * 16 + dc * 4);
        half4 pk4;
        pk4[0] = (_Float16)(acc[0] * invv);
        pk4[1] = (_Float16)(acc[1] * invv);
        pk4[2] = (_Float16)(acc[2] * invv);
        pk4[3] = (_Float16)(acc[3] * invv);
        *reinterpret_cast<half4*>(op + dc * 16 + quad * 4) = pk4;
      }
    }
  }
}

// ---------------------------------------------------------------------------
// Kernel 3: out = attnout @ W^T + b  (M=8192, N=512, K=512), fp32 out.
// LDS-staged, BK=128, pre-converted wb f16 + XCD SWIZZLE: XCD x owns m-tiles
// [16x,16x+16) x all 8 n-tiles -> per-XCD footprint = 1 MB ao + 0.5 MB wb
// (L2-resident). (256,4): 4 blocks/CU -> all 1024 blocks resident.
// ---------------------------------------------------------------------------
__global__ __launch_bounds__(256, 4) void proj_kernel(
    const _Float16* __restrict__ ao, const _Float16* __restrict__ wb,
    const float* __restrict__ bias, float* __restrict__ out) {
  const int tid = threadIdx.x;
  const int wave = tid >> 6, lane = tid & 63;
  const int col = lane & 15, quad = lane >> 4;
  // swizzle: 1024 wgs = 128 m-tiles x 8 n-tiles
  const int wg = blockIdx.x + 128 * blockIdx.y;
  const int xcd = wg & 7, slot = wg >> 3;       // slot in [0,128)
  const int m0 = (xcd * 16 + (slot >> 3)) * 64;
  const int n0 = (slot & 7) * 64;
  __shared__ short at[64 * 136];
  __shared__ short bt[64 * 136];

  const int srw = tid >> 4;        // 0..15
  const int soff = (tid & 15) * 8; // 0..120

  short8 ap_[4], wp_[4];
#pragma unroll
  for (int it = 0; it < 4; ++it) {
    int row = it * 16 + srw;
    ap_[it] = ld8(ao + (size_t)(m0 + row) * E_ + soff);
    wp_[it] = ld8(wb + (size_t)(n0 + row) * E_ + soff);
  }

  f32x4 acc[4] = {{0.f,0.f,0.f,0.f},{0.f,0.f,0.f,0.f},{0.f,0.f,0.f,0.f},{0.f,0.f,0.f,0.f}};

  for (int k0 = 0; k0 < E_; k0 += 128) {
#pragma unroll
    for (int it = 0; it < 4; ++it) {
      int row = it * 16 + srw;
      *reinterpret_cast<short8*>(at + row * 136 + soff) = ap_[it];
      *reinterpret_cast<short8*>(bt + row * 136 + soff) = wp_[it];
    }
    __syncthreads();
    if (k0 + 128 < E_) {
#pragma unroll
      for (int it = 0; it < 4; ++it) {
        int row = it * 16 + srw;
        ap_[it] = ld8(ao + (size_t)(m0 + row) * E_ + k0 + 128 + soff);
        wp_[it] = ld8(wb + (size_t)(n0 + row) * E_ + k0 + 128 + soff);
      }
    }
#pragma unroll
    for (int ks = 0; ks < 4; ++ks) {
      half8 a = *reinterpret_cast<const half8*>(at + (wave * 16 + col) * 136 + ks * 32 + quad * 8);
#pragma unroll
      for (int f = 0; f < 4; ++f) {
        half8 bb = *reinterpret_cast<const half8*>(bt + (f * 16 + col) * 136 + ks * 32 + quad * 8);
        acc[f] = __builtin_amdgcn_mfma_f32_16x16x32_f16(a, bb, acc[f], 0, 0, 0);
      }
    }
    __syncthreads();
  }

#pragma unroll
  for (int f = 0; f < 4; ++f) {
    float bv = bias[n0 + f * 16 + col];
#pragma unroll
    for (int r = 0; r < 4; ++r) {
      int row = m0 + wave * 16 + quad * 4 + r;
      out[(size_t)row * E_ + n0 + f * 16 + col] = acc[f][r] + bv;
    }
  }
}

// ---------------------------------------------------------------------------
// ws layout (~25.1 MB):
//   [0)        kA  f16 frag-order [B*H][64G][4][512]   8388608 B
//   [8388608)  vA  f16 frag-order                      8388608 B
//   [16777216) ao  f16 [B,S,E]                         8388608 B
//   [25165824) wb  f16 [E,E]                            524288 B
// ---------------------------------------------------------------------------
extern "C" void kernel_launch(void* const* d_in, const int* in_sizes, int n_in,
                              void* d_out, int out_size, void* d_ws, size_t ws_size,
                              hipStream_t stream) {
  const float* x = (const float*)d_in[0];
  const float* theta = (const float*)d_in[1];
  const float* W = (const float*)d_in[2];
  const float* bias = (const float*)d_in[3];
  float* out = (float*)d_out;
  char* ws = (char*)d_ws;
  const size_t gsz = (size_t)B_ * H_ * S_ * DK_ * 2;  // 8388608
  _Float16* kA = (_Float16*)ws;
  _Float16* vA = (_Float16*)(ws + gsz);
  _Float16* ao = (_Float16*)(ws + 2 * gsz);
  _Float16* wb = (_Float16*)(ws + 3 * gsz);

  // prep_w fused into prep_g as the blockIdx.y == B*H band (one fewer dispatch)
  prep_g_kernel<<<dim3(S_ / 64, B_ * H_ + 1), 256, 0, stream>>>(x, theta, W, kA, vA, wb);
  attn_kernel<<<dim3(32, 16), 256, 0, stream>>>(kA, vA, ao);
  proj_kernel<<<dim3((B_ * S_) / 64, E_ / 64), 256, 0, stream>>>(ao, wb, bias, out);
}

// Round 5
// 120.598 us; speedup vs baseline: 1.0100x; 1.0100x over previous
//
#include <hip/hip_runtime.h>
#include <hip/hip_bf16.h>
#include <math.h>

// Problem constants (from reference): B=4, S=2048, E=512, H=8, DK=64
#define B_ 4
#define S_ 2048
#define E_ 512
#define H_ 8
#define DK_ 64

typedef __attribute__((ext_vector_type(8))) short short8;    // 8x16b (4 VGPRs)
typedef __attribute__((ext_vector_type(4))) float f32x4;     // MFMA C/D frag
typedef _Float16 half8 __attribute__((ext_vector_type(8)));  // 8 f16
typedef _Float16 half4 __attribute__((ext_vector_type(4)));  // 4 f16
typedef __fp16 fp16x2 __attribute__((ext_vector_type(2)));   // cvt_pkrtz result
typedef unsigned uint4v __attribute__((ext_vector_type(4)));

__device__ inline short8 ld8(const void* p) {
  return *reinterpret_cast<const short8*>(p);
}
__device__ inline half8 ld8h(const void* p) {
  return *reinterpret_cast<const half8*>(p);
}

static __device__ inline unsigned pk2(float a, float b) {
  fp16x2 h = __builtin_amdgcn_cvt_pkrtz(a, b);  // v_cvt_pkrtz_f16_f32
  return __builtin_bit_cast(unsigned, h);
}
static __device__ inline half8 pack8(float p0, float p1, float p2, float p3,
                                     float p4, float p5, float p6, float p7) {
  uint4v u;
  u[0] = pk2(p0, p1); u[1] = pk2(p2, p3);
  u[2] = pk2(p4, p5); u[3] = pk2(p6, p7);
  return __builtin_bit_cast(half8, u);
}

// ---------------------------------------------------------------------------
// Fragment-order layouts (R8/R9): kA = QK A/B-operand order with the key
// permutation that makes QK C-tiles concatenate into the PV K=32 B-operand;
// vA = V^T A-operand order. Waves load frags as coalesced 1KB dwordx4. No
// LDS, no barriers in the attention K-loop.
// R13 LESSON: 32-row q-blocks double per-MFMA load overhead; q-tile stays 64.
// R16: TAIL FIX — attn 128-thread blocks (2 waves x 1024 keys), 6 blk/CU ->
// all 1024 blocks co-resident, zero tail. Measured -3.1 us (session best
// 120.9). R17 LESSON: L1 pairing (4-wave blocks, shared key-half streams)
// falsified — 3 blk/CU x 16 KB/iter = 48 KB live > 32 KB L1, cross-block
// eviction defeats dedup; +0.9 us. Reverted to R16 operating point.
// ---------------------------------------------------------------------------

// ---------------------------------------------------------------------------
// Kernel 1: cos(x+theta) -> kA (frag order, serves Q and K) + vA (frag order).
// Band blockIdx.y == B*H additionally converts W (fp32) -> wb (f16).
// ---------------------------------------------------------------------------
__global__ __launch_bounds__(256) void prep_g_kernel(
    const float* __restrict__ x, const float* __restrict__ theta,
    const float* __restrict__ W, _Float16* __restrict__ kA,
    _Float16* __restrict__ vA, _Float16* __restrict__ wb) {
  const int tid = threadIdx.x;

  // ---- fused prep_w band: 32 blocks convert E*E = 262144 floats -> f16 ----
  if (blockIdx.y == B_ * H_) {
    const int base = (blockIdx.x * 256 + tid) * 8;
#pragma unroll
    for (int it = 0; it < 4; ++it) {
      const int i = base + it * 65536;
      float4 a = *reinterpret_cast<const float4*>(W + i);
      float4 c = *reinterpret_cast<const float4*>(W + i + 4);
      half8 v;
      v[0]=(_Float16)a.x; v[1]=(_Float16)a.y; v[2]=(_Float16)a.z; v[3]=(_Float16)a.w;
      v[4]=(_Float16)c.x; v[5]=(_Float16)c.y; v[6]=(_Float16)c.z; v[7]=(_Float16)c.w;
      *reinterpret_cast<half8*>(wb + i) = v;
    }
    return;
  }

  const int bh = blockIdx.y;
  const int b = bh >> 3, h = bh & 7;
  const int s0 = blockIdx.x * 64;
  const int wave = tid >> 6, lane = tid & 63;
  const int col = lane & 15, quad = lane >> 4;
  __shared__ _Float16 tile[64 * 72];

  // float4 x-loads (16B/lane, G13): thread's dc4 is iteration-invariant, so
  // theta loads hoist to 4 registers.
  const float* xp = x + ((size_t)(b * S_ + s0)) * E_ + h * DK_;
  const int dc4 = (tid & 15) * 4;
  const float4 th = *reinterpret_cast<const float4*>(theta + dc4);
#pragma unroll
  for (int it = 0; it < 4; ++it) {
    const int sr = it * 16 + (tid >> 4);
    float4 xv = *reinterpret_cast<const float4*>(xp + (size_t)sr * E_ + dc4);
    half4 hv;
    hv[0] = (_Float16)__cosf(xv.x + th.x);
    hv[1] = (_Float16)__cosf(xv.y + th.y);
    hv[2] = (_Float16)__cosf(xv.z + th.z);
    hv[3] = (_Float16)__cosf(xv.w + th.w);
    *reinterpret_cast<half4*>(tile + sr * 72 + dc4) = hv;
  }
  __syncthreads();

  _Float16* kb = kA + (size_t)bh * (S_ * DK_);
  _Float16* vb = vA + (size_t)bh * (S_ * DK_);
  const int Gbase = s0 >> 5;
  // kA: 8 chunks (2 Gl x 2 g x 2 hh); wave handles chunk wave + it2*4
#pragma unroll
  for (int it2 = 0; it2 < 2; ++it2) {
    int c = wave + it2 * 4;
    int Gl = c >> 2, g = (c >> 1) & 1, hh = c & 1;
    int ploc = Gl * 32 + ((col >> 2) << 3) + g * 4 + (col & 3);
    half8 v = ld8h(tile + ploc * 72 + hh * 32 + quad * 8);
    *reinterpret_cast<half8*>(
        kb + ((size_t)(Gbase + Gl) * 2048 + (g * 2 + hh) * 512 + lane * 8)) = v;
  }
  // vA: 8 chunks (2 Gl x 4 dcc); transposed gather from tile
#pragma unroll
  for (int it2 = 0; it2 < 2; ++it2) {
    int c = wave + it2 * 4;
    int Gl = c >> 2, dcc = c & 3;
    half8 v;
#pragma unroll
    for (int j = 0; j < 8; ++j)
      v[j] = tile[(Gl * 32 + quad * 8 + j) * 72 + dcc * 16 + col];
    *reinterpret_cast<half8*>(
        vb + ((size_t)(Gbase + Gl) * 2048 + dcc * 512 + lane * 8)) = v;
  }
}

// ---------------------------------------------------------------------------
// Kernel 2: attention — barrier-free LDS-free K-loop, 64 q-rows/block, XCD
// swizzle (XCD x owns bh [4x,4x+4): kA+vA footprint 2 MB/XCD, L2-resident).
// R16: 128-thread blocks (2 waves x 1024-key stripes, 32 its). VGPR ~160
// fits (128,3) cap -> 6 blocks/CU -> all 1024 blocks co-resident (no tail).
// ---------------------------------------------------------------------------
__global__ __launch_bounds__(128, 3) void attn_kernel(
    const _Float16* __restrict__ kA, const _Float16* __restrict__ vA,
    _Float16* __restrict__ ao) {
  const int tid = threadIdx.x;
  const int wave = tid >> 6, lane = tid & 63;
  const int col = lane & 15, quad = lane >> 4;
  const int wg = blockIdx.x + 32 * blockIdx.y;
  const int xcd = wg & 7, slot = wg >> 3;
  const int bh = xcd * 4 + (slot >> 5);
  const int q0 = (slot & 31) * 64;
  const _Float16* kb = kA + (size_t)bh * (S_ * DK_);
  const _Float16* vb = vA + (size_t)bh * (S_ * DK_);

  // Q frags: qc=(Gq,g): chunk ((q0>>5)+Gq, g, h), scaled by C1
  const _Float16 hC1 = (_Float16)0.18033688011112042f;  // 0.125*log2(e)
  half8 qa[4][2];
#pragma unroll
  for (int qc = 0; qc < 4; ++qc)
#pragma unroll
    for (int hh = 0; hh < 2; ++hh)
      qa[qc][hh] = ld8h(kb + (size_t)((q0 >> 5) + (qc >> 1)) * 2048 +
                        ((qc & 1) * 2 + hh) * 512 + lane * 8) * hC1;

  const half8 kOnes = {(_Float16)1, (_Float16)1, (_Float16)1, (_Float16)1,
                       (_Float16)1, (_Float16)1, (_Float16)1, (_Float16)1};

  f32x4 o[4][4];
  f32x4 ol[4];  // softmax denominators via ones-MFMA (rows redundant)
#pragma unroll
  for (int qc = 0; qc < 4; ++qc) {
#pragma unroll
    for (int dc = 0; dc < 4; ++dc) o[qc][dc] = f32x4{0.f, 0.f, 0.f, 0.f};
    ol[qc] = f32x4{0.f, 0.f, 0.f, 0.f};
  }

  // wave's key stripe: 1024 keys = 32 G-chunks
  const _Float16* kw = kb + (size_t)wave * 32 * 2048 + lane * 8;
  const _Float16* vw = vb + (size_t)wave * 32 * 2048 + lane * 8;

  for (int it = 0; it < 32; ++it) {
    const _Float16* kit = kw + it * 2048;
    const _Float16* vit = vw + it * 2048;
    half8 kf00 = ld8h(kit);
    half8 kf01 = ld8h(kit + 512);
    half8 kf10 = ld8h(kit + 1024);
    half8 kf11 = ld8h(kit + 1536);
    half8 vf0 = ld8h(vit);
    half8 vf1 = ld8h(vit + 512);
    half8 vf2 = ld8h(vit + 1024);
    half8 vf3 = ld8h(vit + 1536);

#pragma unroll
    for (int qc = 0; qc < 4; ++qc) {
      f32x4 z0{0.f, 0.f, 0.f, 0.f}, z1{0.f, 0.f, 0.f, 0.f};
      __builtin_amdgcn_s_setprio(1);
      z0 = __builtin_amdgcn_mfma_f32_16x16x32_f16(kf00, qa[qc][0], z0, 0, 0, 0);
      z0 = __builtin_amdgcn_mfma_f32_16x16x32_f16(kf01, qa[qc][1], z0, 0, 0, 0);
      z1 = __builtin_amdgcn_mfma_f32_16x16x32_f16(kf10, qa[qc][0], z1, 0, 0, 0);
      z1 = __builtin_amdgcn_mfma_f32_16x16x32_f16(kf11, qa[qc][1], z1, 0, 0, 0);
      __builtin_amdgcn_s_setprio(0);
      float p0 = __builtin_amdgcn_exp2f(z0[0]);
      float p1 = __builtin_amdgcn_exp2f(z0[1]);
      float p2 = __builtin_amdgcn_exp2f(z0[2]);
      float p3 = __builtin_amdgcn_exp2f(z0[3]);
      float p4 = __builtin_amdgcn_exp2f(z1[0]);
      float p5 = __builtin_amdgcn_exp2f(z1[1]);
      float p6 = __builtin_amdgcn_exp2f(z1[2]);
      float p7 = __builtin_amdgcn_exp2f(z1[3]);
      half8 pf = pack8(p0, p1, p2, p3, p4, p5, p6, p7);
      __builtin_amdgcn_s_setprio(1);
      o[qc][0] = __builtin_amdgcn_mfma_f32_16x16x32_f16(vf0, pf, o[qc][0], 0, 0, 0);
      o[qc][1] = __builtin_amdgcn_mfma_f32_16x16x32_f16(vf1, pf, o[qc][1], 0, 0, 0);
      o[qc][2] = __builtin_amdgcn_mfma_f32_16x16x32_f16(vf2, pf, o[qc][2], 0, 0, 0);
      o[qc][3] = __builtin_amdgcn_mfma_f32_16x16x32_f16(vf3, pf, o[qc][3], 0, 0, 0);
      ol[qc] = __builtin_amdgcn_mfma_f32_16x16x32_f16(kOnes, pf, ol[qc], 0, 0, 0);
      __builtin_amdgcn_s_setprio(0);
    }
  }

  // ---- one-time cross-wave reduction (2 waves) ----
  // ol[qc][0] holds this wave's 1024-key partial denominator for q=col
  // (quad-redundant) -> no intra-wave shuffle needed.
  __shared__ float reds[2048];  // 8 KB (6 blocks/CU -> 48 KB, fits)
  if (quad == 0) {
#pragma unroll
    for (int qc = 0; qc < 4; ++qc) reds[(wave * 4 + qc) * 16 + col] = ol[qc][0];
  }
  __syncthreads();
  // wave w reduces/stores qc = w (passes 0,1) and qc = w+2 (passes 2,3)
  float ltotA = reds[(0 * 4 + wave) * 16 + col] + reds[(1 * 4 + wave) * 16 + col];
  float ltotB = reds[(0 * 4 + wave + 2) * 16 + col] + reds[(1 * 4 + wave + 2) * 16 + col];
  float invA = __builtin_amdgcn_rcpf(ltotA);
  float invB = __builtin_amdgcn_rcpf(ltotB);

  const int b = bh >> 3, h = bh & 7;
  // store row carries the kA q-permutation: qc=(Gq,g), col -> q
  // qrow(qc) = q0 + ((qc>>1)<<5) + ((col>>2)<<3) + (qc&1)*4 + (col&3)
  const int qrowA = q0 + ((col >> 2) << 3) + wave * 4 + (col & 3);          // qc = wave
  const int qrowB = qrowA + 32;                                            // qc = wave+2
  _Float16* opA = ao + ((size_t)b * S_ + qrowA) * E_ + h * DK_;
  _Float16* opB = ao + ((size_t)b * S_ + qrowB) * E_ + h * DK_;
  __syncthreads();  // ltot reads done before reds is overwritten
#pragma unroll
  for (int p = 0; p < 4; ++p) {
    if (p) __syncthreads();  // previous pass's readers done
#pragma unroll
    for (int dc = 0; dc < 4; ++dc)
      *reinterpret_cast<f32x4*>(reds + wave * 1024 + lane * 16 + dc * 4) = o[p][dc];
    __syncthreads();
    if (wave == (p & 1)) {  // wave reduces its own qc (p<2: qc=wave; else wave+2)
      float invv = (p < 2) ? invA : invB;
      _Float16* op = (p < 2) ? opA : opB;
#pragma unroll
      for (int dc = 0; dc < 4; ++dc) {
        f32x4 acc = *reinterpret_cast<const f32x4*>(reds + lane * 16 + dc * 4);
        acc = acc + *reinterpret_cast<const f32x4*>(reds + 1024 + lane * 16 + dc * 4);
        half4 pk4;
        pk4[0] = (_Float16)(acc[0] * invv);
        pk4[1] = (_Float16)(acc[1] * invv);
        pk4[2] = (_Float16)(acc[2] * invv);
        pk4[3] = (_Float16)(acc[3] * invv);
        *reinterpret_cast<half4*>(op + dc * 16 + quad * 4) = pk4;
      }
    }
  }
}

// ---------------------------------------------------------------------------
// Kernel 3: out = attnout @ W^T + b  (M=8192, N=512, K=512), fp32 out.
// LDS-staged, BK=128, pre-converted wb f16 + XCD SWIZZLE: XCD x owns m-tiles
// [16x,16x+16) x all 8 n-tiles -> per-XCD footprint = 1 MB ao + 0.5 MB wb
// (L2-resident). (256,4): 4 blocks/CU -> all 1024 blocks resident.
// ---------------------------------------------------------------------------
__global__ __launch_bounds__(256, 4) void proj_kernel(
    const _Float16* __restrict__ ao, const _Float16* __restrict__ wb,
    const float* __restrict__ bias, float* __restrict__ out) {
  const int tid = threadIdx.x;
  const int wave = tid >> 6, lane = tid & 63;
  const int col = lane & 15, quad = lane >> 4;
  // swizzle: 1024 wgs = 128 m-tiles x 8 n-tiles
  const int wg = blockIdx.x + 128 * blockIdx.y;
  const int xcd = wg & 7, slot = wg >> 3;       // slot in [0,128)
  const int m0 = (xcd * 16 + (slot >> 3)) * 64;
  const int n0 = (slot & 7) * 64;
  __shared__ short at[64 * 136];
  __shared__ short bt[64 * 136];

  const int srw = tid >> 4;        // 0..15
  const int soff = (tid & 15) * 8; // 0..120

  short8 ap_[4], wp_[4];
#pragma unroll
  for (int it = 0; it < 4; ++it) {
    int row = it * 16 + srw;
    ap_[it] = ld8(ao + (size_t)(m0 + row) * E_ + soff);
    wp_[it] = ld8(wb + (size_t)(n0 + row) * E_ + soff);
  }

  f32x4 acc[4] = {{0.f,0.f,0.f,0.f},{0.f,0.f,0.f,0.f},{0.f,0.f,0.f,0.f},{0.f,0.f,0.f,0.f}};

  for (int k0 = 0; k0 < E_; k0 += 128) {
#pragma unroll
    for (int it = 0; it < 4; ++it) {
      int row = it * 16 + srw;
      *reinterpret_cast<short8*>(at + row * 136 + soff) = ap_[it];
      *reinterpret_cast<short8*>(bt + row * 136 + soff) = wp_[it];
    }
    __syncthreads();
    if (k0 + 128 < E_) {
#pragma unroll
      for (int it = 0; it < 4; ++it) {
        int row = it * 16 + srw;
        ap_[it] = ld8(ao + (size_t)(m0 + row) * E_ + k0 + 128 + soff);
        wp_[it] = ld8(wb + (size_t)(n0 + row) * E_ + k0 + 128 + soff);
      }
    }
#pragma unroll
    for (int ks = 0; ks < 4; ++ks) {
      half8 a = *reinterpret_cast<const half8*>(at + (wave * 16 + col) * 136 + ks * 32 + quad * 8);
#pragma unroll
      for (int f = 0; f < 4; ++f) {
        half8 bb = *reinterpret_cast<const half8*>(bt + (f * 16 + col) * 136 + ks * 32 + quad * 8);
        acc[f] = __builtin_amdgcn_mfma_f32_16x16x32_f16(a, bb, acc[f], 0, 0, 0);
      }
    }
    __syncthreads();
  }

#pragma unroll
  for (int f = 0; f < 4; ++f) {
    float bv = bias[n0 + f * 16 + col];
#pragma unroll
    for (int r = 0; r < 4; ++r) {
      int row = m0 + wave * 16 + quad * 4 + r;
      out[(size_t)row * E_ + n0 + f * 16 + col] = acc[f][r] + bv;
    }
  }
}

// ---------------------------------------------------------------------------
// ws layout (~25.1 MB):
//   [0)        kA  f16 frag-order [B*H][64G][4][512]   8388608 B
//   [8388608)  vA  f16 frag-order                      8388608 B
//   [16777216) ao  f16 [B,S,E]                         8388608 B
//   [25165824) wb  f16 [E,E]                            524288 B
// ---------------------------------------------------------------------------
extern "C" void kernel_launch(void* const* d_in, const int* in_sizes, int n_in,
                              void* d_out, int out_size, void* d_ws, size_t ws_size,
                              hipStream_t stream) {
  const float* x = (const float*)d_in[0];
  const float* theta = (const float*)d_in[1];
  const float* W = (const float*)d_in[2];
  const float* bias = (const float*)d_in[3];
  float* out = (float*)d_out;
  char* ws = (char*)d_ws;
  const size_t gsz = (size_t)B_ * H_ * S_ * DK_ * 2;  // 8388608
  _Float16* kA = (_Float16*)ws;
  _Float16* vA = (_Float16*)(ws + gsz);
  _Float16* ao = (_Float16*)(ws + 2 * gsz);
  _Float16* wb = (_Float16*)(ws + 3 * gsz);

  // prep_w fused into prep_g as the blockIdx.y == B*H band (one fewer dispatch)
  prep_g_kernel<<<dim3(S_ / 64, B_ * H_ + 1), 256, 0, stream>>>(x, theta, W, kA, vA, wb);
  attn_kernel<<<dim3(32, 32), 128, 0, stream>>>(kA, vA, ao);
  proj_kernel<<<dim3((B_ * S_) / 64, E_ / 64), 256, 0, stream>>>(ao, wb, bias, out);
}